// Round 1
// baseline (439.610 us; speedup 1.0000x reference)
//
#include <hip/hip_runtime.h>

#define B_  4
#define S_  2048
#define D_  1024
#define H_  16
#define HD_ 64
#define M_  (B_*S_)   // 8192

typedef unsigned short u16;
typedef __bf16 bf16x8 __attribute__((ext_vector_type(8)));
typedef float  f32x4  __attribute__((ext_vector_type(4)));

__device__ __forceinline__ u16 f2bf(float f) {
  unsigned int u = __float_as_uint(f);
  u += 0x7fffu + ((u >> 16) & 1u);
  return (u16)(u >> 16);
}

// ---------------- convert x (fp32 -> bf16), vectorized ----------------
__global__ void cvt_f32_bf16(const float* __restrict__ in, u16* __restrict__ out, int n4) {
  int i = blockIdx.x * 256 + threadIdx.x;
  if (i < n4) {
    float4 v = ((const float4*)in)[i];
    unsigned int lo = (unsigned int)f2bf(v.x) | ((unsigned int)f2bf(v.y) << 16);
    unsigned int hi = (unsigned int)f2bf(v.z) | ((unsigned int)f2bf(v.w) << 16);
    ((uint2*)out)[i] = make_uint2(lo, hi);
  }
}

// ------------- transpose fp32 [R][C] -> bf16 [C][R] -------------------
__global__ void transpose_w(const float* __restrict__ in, u16* __restrict__ out, int R, int C) {
  __shared__ float tile[32][33];
  int c0 = blockIdx.x * 32, r0 = blockIdx.y * 32;
  int tx = threadIdx.x, ty = threadIdx.y;
  #pragma unroll
  for (int i = 0; i < 4; i++)
    tile[ty + i*8][tx] = in[(size_t)(r0 + ty + i*8) * C + c0 + tx];
  __syncthreads();
  #pragma unroll
  for (int i = 0; i < 4; i++)
    out[(size_t)(c0 + ty + i*8) * R + r0 + tx] = f2bf(tile[tx][ty + i*8]);
}

// ------------- transpose V bf16: [bh][2048][64] -> [bh][64][2048] -----
__global__ void transpose_v(const u16* __restrict__ in, u16* __restrict__ out) {
  __shared__ u16 tile[32][33];
  size_t base = (size_t)blockIdx.z * S_ * HD_;
  int c0 = blockIdx.x * 32;   // hd
  int r0 = blockIdx.y * 32;   // s
  int tx = threadIdx.x, ty = threadIdx.y;
  #pragma unroll
  for (int i = 0; i < 4; i++)
    tile[ty + i*8][tx] = in[base + (size_t)(r0 + ty + i*8) * HD_ + c0 + tx];
  __syncthreads();
  #pragma unroll
  for (int i = 0; i < 4; i++)
    out[base + (size_t)(c0 + ty + i*8) * S_ + r0 + tx] = tile[tx][ty + i*8];
}

// ---------------- QKV GEMM: [8192,1024]x[1024,3072] -------------------
// X bf16 [M][K], WT bf16 [N][K]. 128x128 tile, BK=32, 4 waves of 64x64.
__global__ __launch_bounds__(256) void gemm_qkv(
    const u16* __restrict__ X, const u16* __restrict__ WT,
    const float* __restrict__ bias,
    u16* __restrict__ qb, u16* __restrict__ kb, u16* __restrict__ vb)
{
  __shared__ u16 Al[128 * 40];   // pad 32->40 (bank spread, keeps 16B align)
  __shared__ u16 Bl[128 * 40];
  const int t = threadIdx.x;
  const int m0 = blockIdx.y * 128;
  const int n0 = blockIdx.x * 128;
  const int wave = t >> 6, lane = t & 63;
  const int wm = (wave >> 1) * 64, wn = (wave & 1) * 64;
  const int lr = lane & 15, quad = lane >> 4;

  f32x4 acc[4][4] = {};
  for (int k0 = 0; k0 < D_; k0 += 32) {
    __syncthreads();
    #pragma unroll
    for (int i = 0; i < 2; i++) {
      int c = t + i * 256;
      int row = c >> 2, ko = (c & 3) * 8;
      *(uint4*)&Al[row * 40 + ko] = *(const uint4*)&X [(size_t)(m0 + row) * D_ + k0 + ko];
      *(uint4*)&Bl[row * 40 + ko] = *(const uint4*)&WT[(size_t)(n0 + row) * D_ + k0 + ko];
    }
    __syncthreads();
    bf16x8 a[4], b[4];
    #pragma unroll
    for (int mt = 0; mt < 4; mt++) a[mt] = *(const bf16x8*)&Al[(wm + mt*16 + lr) * 40 + quad * 8];
    #pragma unroll
    for (int nt = 0; nt < 4; nt++) b[nt] = *(const bf16x8*)&Bl[(wn + nt*16 + lr) * 40 + quad * 8];
    #pragma unroll
    for (int mt = 0; mt < 4; mt++)
      #pragma unroll
      for (int nt = 0; nt < 4; nt++)
        acc[mt][nt] = __builtin_amdgcn_mfma_f32_16x16x32_bf16(a[mt], b[nt], acc[mt][nt], 0, 0, 0);
  }
  #pragma unroll
  for (int mt = 0; mt < 4; mt++)
  #pragma unroll
  for (int nt = 0; nt < 4; nt++)
  #pragma unroll
  for (int r = 0; r < 4; r++) {
    int m = m0 + wm + mt * 16 + quad * 4 + r;
    int n = n0 + wn + nt * 16 + lr;
    float v = acc[mt][nt][r] + bias[n];
    int which = n >> 10;                 // 0=q 1=k 2=v
    int h = (n >> 6) & 15, hd = n & 63;
    int bb = m >> 11, s = m & 2047;
    size_t idx = (((size_t)(bb * H_ + h) * S_) + s) * HD_ + hd;
    if (which == 0)      qb[idx] = f2bf(v * 0.125f);   // fold 1/sqrt(HD)
    else if (which == 1) kb[idx] = f2bf(v);
    else                 vb[idx] = f2bf(v);
  }
}

// ---------------- proj GEMM: [8192,1024]x[1024,1024] + bias -> fp32 ---
__global__ __launch_bounds__(256) void gemm_proj(
    const u16* __restrict__ X, const u16* __restrict__ WT,
    const float* __restrict__ bias, float* __restrict__ out)
{
  __shared__ u16 Al[128 * 40];
  __shared__ u16 Bl[128 * 40];
  const int t = threadIdx.x;
  const int m0 = blockIdx.y * 128;
  const int n0 = blockIdx.x * 128;
  const int wave = t >> 6, lane = t & 63;
  const int wm = (wave >> 1) * 64, wn = (wave & 1) * 64;
  const int lr = lane & 15, quad = lane >> 4;

  f32x4 acc[4][4] = {};
  for (int k0 = 0; k0 < D_; k0 += 32) {
    __syncthreads();
    #pragma unroll
    for (int i = 0; i < 2; i++) {
      int c = t + i * 256;
      int row = c >> 2, ko = (c & 3) * 8;
      *(uint4*)&Al[row * 40 + ko] = *(const uint4*)&X [(size_t)(m0 + row) * D_ + k0 + ko];
      *(uint4*)&Bl[row * 40 + ko] = *(const uint4*)&WT[(size_t)(n0 + row) * D_ + k0 + ko];
    }
    __syncthreads();
    bf16x8 a[4], b[4];
    #pragma unroll
    for (int mt = 0; mt < 4; mt++) a[mt] = *(const bf16x8*)&Al[(wm + mt*16 + lr) * 40 + quad * 8];
    #pragma unroll
    for (int nt = 0; nt < 4; nt++) b[nt] = *(const bf16x8*)&Bl[(wn + nt*16 + lr) * 40 + quad * 8];
    #pragma unroll
    for (int mt = 0; mt < 4; mt++)
      #pragma unroll
      for (int nt = 0; nt < 4; nt++)
        acc[mt][nt] = __builtin_amdgcn_mfma_f32_16x16x32_bf16(a[mt], b[nt], acc[mt][nt], 0, 0, 0);
  }
  #pragma unroll
  for (int mt = 0; mt < 4; mt++)
  #pragma unroll
  for (int nt = 0; nt < 4; nt++)
  #pragma unroll
  for (int r = 0; r < 4; r++) {
    int m = m0 + wm + mt * 16 + quad * 4 + r;
    int n = n0 + wn + nt * 16 + lr;
    out[(size_t)m * D_ + n] = acc[mt][nt][r] + bias[n];
  }
}

// ---------------- flash attention ------------------------------------
// grid (S/64, B*H), 256 thr. Wave w owns Q rows [w*16, w*16+16).
// q,k: [bh][S][64] bf16 (q pre-scaled). vt: [bh][64][S] bf16.
// out: bf16 [B][S][H][HD] flattened as [M][D].
__global__ __launch_bounds__(256) void attn(
    const u16* __restrict__ qb, const u16* __restrict__ kb,
    const u16* __restrict__ vt, u16* __restrict__ ob)
{
  __shared__ u16 Kl[64 * 72];     // [s_k][hd], pad 64->72
  __shared__ u16 Vl[64 * 72];     // [hd][s_k], pad
  __shared__ u16 Pl[4][16 * 72];  // per-wave P, [q_row][s_k], pad
  const int t = threadIdx.x;
  const int w = t >> 6, lane = t & 63;
  const int lr = lane & 15, quad = lane >> 4;
  const int qt = blockIdx.x;           // 0..31
  const int bh = blockIdx.y;           // 0..63
  const u16* q = qb + (size_t)bh * S_ * HD_;
  const u16* k = kb + (size_t)bh * S_ * HD_;
  const u16* v = vt + (size_t)bh * HD_ * S_;
  const int s0 = qt * 64;

  bf16x8 qa[2];
  #pragma unroll
  for (int kk = 0; kk < 2; kk++)
    qa[kk] = *(const bf16x8*)&q[(size_t)(s0 + w * 16 + lr) * HD_ + kk * 32 + quad * 8];

  f32x4 o[4] = {};
  float rowmax[4], rowsum[4];
  #pragma unroll
  for (int r = 0; r < 4; r++) { rowmax[r] = -1e30f; rowsum[r] = 0.f; }

  for (int k0 = 0; k0 < S_; k0 += 64) {
    __syncthreads();
    #pragma unroll
    for (int i = 0; i < 2; i++) {
      int c = t + i * 256;
      int row = c >> 3, co = (c & 7) * 8;
      *(uint4*)&Kl[row * 72 + co] = *(const uint4*)&k[(size_t)(k0 + row) * HD_ + co];
      *(uint4*)&Vl[row * 72 + co] = *(const uint4*)&v[(size_t)row * S_ + k0 + co];
    }
    __syncthreads();
    // S = Q K^T  (16 q-rows x 64 keys per wave)
    f32x4 sf[4];
    #pragma unroll
    for (int nt = 0; nt < 4; nt++) {
      f32x4 z = {};
      #pragma unroll
      for (int kk = 0; kk < 2; kk++) {
        bf16x8 bk = *(const bf16x8*)&Kl[(nt * 16 + lr) * 72 + kk * 32 + quad * 8];
        z = __builtin_amdgcn_mfma_f32_16x16x32_bf16(qa[kk], bk, z, 0, 0, 0);
      }
      sf[nt] = z;
    }
    // online softmax: rows quad*4+r, cols spread over nt and 16 lanes of quad
    float alpha[4];
    #pragma unroll
    for (int r = 0; r < 4; r++) {
      float mx = fmaxf(fmaxf(sf[0][r], sf[1][r]), fmaxf(sf[2][r], sf[3][r]));
      #pragma unroll
      for (int off = 1; off < 16; off <<= 1) mx = fmaxf(mx, __shfl_xor(mx, off));
      float mnew = fmaxf(rowmax[r], mx);
      alpha[r] = __expf(rowmax[r] - mnew);
      rowmax[r] = mnew;
    }
    float rs[4] = {0.f, 0.f, 0.f, 0.f};
    #pragma unroll
    for (int nt = 0; nt < 4; nt++)
      #pragma unroll
      for (int r = 0; r < 4; r++) {
        float p = __expf(sf[nt][r] - rowmax[r]);
        sf[nt][r] = p;
        rs[r] += p;
      }
    #pragma unroll
    for (int r = 0; r < 4; r++) {
      #pragma unroll
      for (int off = 1; off < 16; off <<= 1) rs[r] += __shfl_xor(rs[r], off);
      rowsum[r] = rowsum[r] * alpha[r] + rs[r];
      o[0][r] *= alpha[r]; o[1][r] *= alpha[r]; o[2][r] *= alpha[r]; o[3][r] *= alpha[r];
    }
    // P: C-layout -> LDS -> A-layout
    #pragma unroll
    for (int nt = 0; nt < 4; nt++)
      #pragma unroll
      for (int r = 0; r < 4; r++)
        Pl[w][(quad * 4 + r) * 72 + nt * 16 + lr] = f2bf(sf[nt][r]);
    __syncthreads();
    // O += P V
    #pragma unroll
    for (int kk = 0; kk < 2; kk++) {
      bf16x8 pa = *(const bf16x8*)&Pl[w][lr * 72 + kk * 32 + quad * 8];
      #pragma unroll
      for (int nt = 0; nt < 4; nt++) {
        bf16x8 bv = *(const bf16x8*)&Vl[(nt * 16 + lr) * 72 + kk * 32 + quad * 8];
        o[nt] = __builtin_amdgcn_mfma_f32_16x16x32_bf16(pa, bv, o[nt], 0, 0, 0);
      }
    }
  }
  // epilogue: out[b][s][h][hd]
  const int b = bh >> 4, h = bh & 15;
  #pragma unroll
  for (int r = 0; r < 4; r++) {
    float inv = 1.0f / rowsum[r];
    int s = s0 + w * 16 + quad * 4 + r;
    size_t rowoff = ((size_t)(b * S_ + s)) * D_ + h * HD_;
    #pragma unroll
    for (int nt = 0; nt < 4; nt++)
      ob[rowoff + nt * 16 + lr] = f2bf(o[nt][r] * inv);
  }
}

extern "C" void kernel_launch(void* const* d_in, const int* in_sizes, int n_in,
                              void* d_out, int out_size, void* d_ws, size_t ws_size,
                              hipStream_t stream) {
  const float* x      = (const float*)d_in[0];
  const float* w_qkv  = (const float*)d_in[1];
  const float* b_qkv  = (const float*)d_in[2];
  const float* w_proj = (const float*)d_in[3];
  const float* b_proj = (const float*)d_in[4];
  float* out = (float*)d_out;

  char* ws = (char*)d_ws;
  u16* xbf    = (u16*)ws; ws += (size_t)M_ * D_ * 2;
  u16* wqkvT  = (u16*)ws; ws += (size_t)3 * D_ * D_ * 2;
  u16* wprojT = (u16*)ws; ws += (size_t)D_ * D_ * 2;
  u16* qbuf   = (u16*)ws; ws += (size_t)M_ * D_ * 2;
  u16* kbuf   = (u16*)ws; ws += (size_t)M_ * D_ * 2;
  u16* vbuf   = (u16*)ws; ws += (size_t)M_ * D_ * 2;
  u16* vtbuf  = (u16*)ws; ws += (size_t)M_ * D_ * 2;
  u16* aobuf  = (u16*)ws; ws += (size_t)M_ * D_ * 2;

  cvt_f32_bf16<<<(M_ * D_ / 4 + 255) / 256, 256, 0, stream>>>(x, xbf, M_ * D_ / 4);
  transpose_w<<<dim3(3 * D_ / 32, D_ / 32), dim3(32, 8), 0, stream>>>(w_qkv, wqkvT, D_, 3 * D_);
  transpose_w<<<dim3(D_ / 32, D_ / 32), dim3(32, 8), 0, stream>>>(w_proj, wprojT, D_, D_);
  gemm_qkv<<<dim3(3 * D_ / 128, M_ / 128), 256, 0, stream>>>(xbf, wqkvT, b_qkv, qbuf, kbuf, vbuf);
  transpose_v<<<dim3(HD_ / 32, S_ / 32, B_ * H_), dim3(32, 8), 0, stream>>>(vbuf, vtbuf);
  attn<<<dim3(S_ / 64, B_ * H_), 256, 0, stream>>>(qbuf, kbuf, vtbuf, aobuf);
  gemm_proj<<<dim3(D_ / 128, M_ / 128), 256, 0, stream>>>(aobuf, wprojT, b_proj, out);
}

// Round 3
// 380.742 us; speedup vs baseline: 1.1546x; 1.1546x over previous
//
#include <hip/hip_runtime.h>

#define B_  4
#define S_  2048
#define D_  1024
#define H_  16
#define HD_ 64
#define M_  (B_*S_)   // 8192
#define QSCALE 0.1803368801111204f   // 0.125 * log2(e): folds softmax scale + exp2 base change

typedef unsigned short u16;
typedef __bf16 bf16x8 __attribute__((ext_vector_type(8)));
typedef float  f32x4  __attribute__((ext_vector_type(4)));
typedef float  f32x16 __attribute__((ext_vector_type(16)));

__device__ __forceinline__ u16 f2bf(float f) {
  unsigned int u = __float_as_uint(f);
  u += 0x7fffu + ((u >> 16) & 1u);
  return (u16)(u >> 16);
}
__device__ __forceinline__ unsigned int packbf2(float lo, float hi) {
  return (unsigned int)f2bf(lo) | ((unsigned int)f2bf(hi) << 16);
}
// async global->LDS, 16B per lane; LDS dest = wave-uniform base + lane*16
__device__ __forceinline__ void gld16(const void* g, void* l) {
  __builtin_amdgcn_global_load_lds(
      (const __attribute__((address_space(1))) unsigned int*)g,
      (__attribute__((address_space(3))) unsigned int*)l, 16, 0, 0);
}
#define MFMA32(a,b,c) __builtin_amdgcn_mfma_f32_32x32x16_bf16(a,b,c,0,0,0)

// ---------------- convert x (fp32 -> bf16) ----------------
__global__ void cvt_f32_bf16(const float* __restrict__ in, u16* __restrict__ out, int n4) {
  int i = blockIdx.x * 256 + threadIdx.x;
  if (i < n4) {
    float4 v = ((const float4*)in)[i];
    unsigned int lo = (unsigned int)f2bf(v.x) | ((unsigned int)f2bf(v.y) << 16);
    unsigned int hi = (unsigned int)f2bf(v.z) | ((unsigned int)f2bf(v.w) << 16);
    ((uint2*)out)[i] = make_uint2(lo, hi);
  }
}

// ------------- transpose fp32 [R][C] -> bf16 [C][R] -------------------
__global__ void transpose_w(const float* __restrict__ in, u16* __restrict__ out, int R, int C) {
  __shared__ float tile[32][33];
  int c0 = blockIdx.x * 32, r0 = blockIdx.y * 32;
  int tx = threadIdx.x, ty = threadIdx.y;
  #pragma unroll
  for (int i = 0; i < 4; i++)
    tile[ty + i*8][tx] = in[(size_t)(r0 + ty + i*8) * C + c0 + tx];
  __syncthreads();
  #pragma unroll
  for (int i = 0; i < 4; i++)
    out[(size_t)(c0 + ty + i*8) * R + r0 + tx] = f2bf(tile[tx][ty + i*8]);
}

// ------------- transpose V bf16: [bh][2048][64] -> [bh][64][2048] -----
__global__ void transpose_v(const u16* __restrict__ in, u16* __restrict__ out) {
  __shared__ u16 tile[32][33];
  size_t base = (size_t)blockIdx.z * S_ * HD_;
  int c0 = blockIdx.x * 32, r0 = blockIdx.y * 32;
  int tx = threadIdx.x, ty = threadIdx.y;
  #pragma unroll
  for (int i = 0; i < 4; i++)
    tile[ty + i*8][tx] = in[base + (size_t)(r0 + ty + i*8) * HD_ + c0 + tx];
  __syncthreads();
  #pragma unroll
  for (int i = 0; i < 4; i++)
    out[base + (size_t)(c0 + ty + i*8) * S_ + r0 + tx] = tile[tx][ty + i*8];
}

// ---------------- QKV GEMM: [8192,1024]x[1024,3072], 32x32x16 MFMA ----
// X bf16 [M][K], WT bf16 [N][K]. 128x128 tile, BK=64, fragment-major LDS + DMA.
__global__ __launch_bounds__(256,2) void gemm_qkv(
    const u16* __restrict__ X, const u16* __restrict__ WT,
    const float* __restrict__ bias,
    u16* __restrict__ qb, u16* __restrict__ kb, u16* __restrict__ vb)
{
  __shared__ u16 As[16*512];  // 16 frags x 1KB (frag id = mf*4+kk)
  __shared__ u16 Bs[16*512];
  const int t = threadIdx.x, w = t >> 6, l = t & 63, l31 = l & 31, h = l >> 5;
  const int m0 = blockIdx.y * 128, n0 = blockIdx.x * 128;
  const u16* Arow = X  + (size_t)(m0 + w*32 + l31) * D_;
  const u16* Brow = WT + (size_t)(n0 + w*32 + l31) * D_;

  f32x16 acc[2][2] = {};
  for (int k0 = 0; k0 < D_; k0 += 64) {
    __syncthreads();
    #pragma unroll
    for (int kk = 0; kk < 4; kk++) {
      gld16(Arow + k0 + kk*16 + h*8, (char*)As + (w*4+kk)*1024);
      gld16(Brow + k0 + kk*16 + h*8, (char*)Bs + (w*4+kk)*1024);
    }
    __syncthreads();
    const int mfb = (w>>1)*2, nfb = (w&1)*2;
    #pragma unroll
    for (int kk = 0; kk < 4; kk++) {
      bf16x8 a0 = *(const bf16x8*)(As + ((mfb+0)*4+kk)*512 + l*8);
      bf16x8 a1 = *(const bf16x8*)(As + ((mfb+1)*4+kk)*512 + l*8);
      bf16x8 b0 = *(const bf16x8*)(Bs + ((nfb+0)*4+kk)*512 + l*8);
      bf16x8 b1 = *(const bf16x8*)(Bs + ((nfb+1)*4+kk)*512 + l*8);
      acc[0][0] = MFMA32(a0, b0, acc[0][0]);
      acc[0][1] = MFMA32(a0, b1, acc[0][1]);
      acc[1][0] = MFMA32(a1, b0, acc[1][0]);
      acc[1][1] = MFMA32(a1, b1, acc[1][1]);
    }
  }
  const int wm = (w>>1)*64, wn = (w&1)*64;
  #pragma unroll
  for (int mt = 0; mt < 2; mt++)
  #pragma unroll
  for (int nt = 0; nt < 2; nt++) {
    int n = n0 + wn + nt*32 + l31;
    float bia = bias[n];
    int which = n >> 10, hh = (n >> 6) & 15, hd = n & 63;
    #pragma unroll
    for (int r = 0; r < 16; r++) {
      int m = m0 + wm + mt*32 + (r&3) + 8*(r>>2) + 4*h;
      float v = acc[mt][nt][r] + bia;
      int bb = m >> 11, s = m & 2047;
      size_t idx = (((size_t)(bb*H_ + hh) * S_) + s) * HD_ + hd;
      if (which == 0)      qb[idx] = f2bf(v * QSCALE);
      else if (which == 1) kb[idx] = f2bf(v);
      else                 vb[idx] = f2bf(v);
    }
  }
}

// ---------------- proj GEMM: [8192,1024]x[1024,1024] + bias -> fp32 ---
__global__ __launch_bounds__(256,2) void gemm_proj(
    const u16* __restrict__ X, const u16* __restrict__ WT,
    const float* __restrict__ bias, float* __restrict__ out)
{
  __shared__ u16 As[16*512];
  __shared__ u16 Bs[16*512];
  const int t = threadIdx.x, w = t >> 6, l = t & 63, l31 = l & 31, h = l >> 5;
  const int m0 = blockIdx.y * 128, n0 = blockIdx.x * 128;
  const u16* Arow = X  + (size_t)(m0 + w*32 + l31) * D_;
  const u16* Brow = WT + (size_t)(n0 + w*32 + l31) * D_;

  f32x16 acc[2][2] = {};
  for (int k0 = 0; k0 < D_; k0 += 64) {
    __syncthreads();
    #pragma unroll
    for (int kk = 0; kk < 4; kk++) {
      gld16(Arow + k0 + kk*16 + h*8, (char*)As + (w*4+kk)*1024);
      gld16(Brow + k0 + kk*16 + h*8, (char*)Bs + (w*4+kk)*1024);
    }
    __syncthreads();
    const int mfb = (w>>1)*2, nfb = (w&1)*2;
    #pragma unroll
    for (int kk = 0; kk < 4; kk++) {
      bf16x8 a0 = *(const bf16x8*)(As + ((mfb+0)*4+kk)*512 + l*8);
      bf16x8 a1 = *(const bf16x8*)(As + ((mfb+1)*4+kk)*512 + l*8);
      bf16x8 b0 = *(const bf16x8*)(Bs + ((nfb+0)*4+kk)*512 + l*8);
      bf16x8 b1 = *(const bf16x8*)(Bs + ((nfb+1)*4+kk)*512 + l*8);
      acc[0][0] = MFMA32(a0, b0, acc[0][0]);
      acc[0][1] = MFMA32(a0, b1, acc[0][1]);
      acc[1][0] = MFMA32(a1, b0, acc[1][0]);
      acc[1][1] = MFMA32(a1, b1, acc[1][1]);
    }
  }
  const int wm = (w>>1)*64, wn = (w&1)*64;
  #pragma unroll
  for (int mt = 0; mt < 2; mt++)
  #pragma unroll
  for (int nt = 0; nt < 2; nt++) {
    int n = n0 + wn + nt*32 + l31;
    float bia = bias[n];
    #pragma unroll
    for (int r = 0; r < 16; r++) {
      int m = m0 + wm + mt*32 + (r&3) + 8*(r>>2) + 4*h;
      out[(size_t)m * D_ + n] = acc[mt][nt][r] + bia;
    }
  }
}

// ---------------- flash attention (S^T trick, 32x32x16) ---------------
// grid (S/128, B*H), 128 threads (2 waves). Wave w owns 64 q-rows.
// q,k: [bh][S][64] bf16 (q pre-scaled by QSCALE). vt: [bh][64][S] bf16.
// out: bf16 [B][S][H*HD].
__global__ __launch_bounds__(128,2) void attn(
    const u16* __restrict__ qb, const u16* __restrict__ kb,
    const u16* __restrict__ vt, u16* __restrict__ ob)
{
  __shared__ u16 Kl[8*512];       // K-tile 64 keys x 64 hd, frag-major (mt*4+kk)
  __shared__ u16 Vl[8*512];       // V-tile 64 hd x 64 keys, frag-major (nt*4+kk2)
  __shared__ float redL[2][64];   // per-wave alpha / 1/l broadcast
  const int t = threadIdx.x, w = t >> 6, l = t & 63, l31 = l & 31, h = l >> 5;
  const int bh = blockIdx.y, b = bh >> 4, hh = bh & 15;
  const int s0 = blockIdx.x * 128 + w * 64;
  const u16* qp = qb + (size_t)bh * S_ * HD_;
  const u16* kp = kb + (size_t)bh * S_ * HD_;
  const u16* vp = vt + (size_t)bh * HD_ * S_;

  // Q B-frags, resident all along: qa[g][kk]: qrow = s0+g*32+l31, hd = kk*16+h*8+j
  bf16x8 qa[2][4];
  #pragma unroll
  for (int g = 0; g < 2; g++)
    #pragma unroll
    for (int kk = 0; kk < 4; kk++)
      qa[g][kk] = *(const bf16x8*)(qp + (size_t)(s0 + g*32 + l31)*HD_ + kk*16 + h*8);

  f32x16 o[2][2] = {};
  float m_[2] = {-1e30f, -1e30f}, l_[2] = {0.f, 0.f};

  for (int k0 = 0; k0 < S_; k0 += 64) {
    __syncthreads();
    #pragma unroll
    for (int j = 0; j < 4; j++) {
      // K frag (mt=w, kk=j): key = k0+w*32+l31, hd bytes (j*16+h*8)*2
      gld16(kp + (size_t)(k0 + w*32 + l31)*HD_ + j*16 + h*8, (char*)Kl + (w*4+j)*1024);
      // V frag (nt=w, kk2=j): hd = w*32+l31, key = k0+j*16+h*8
      gld16(vp + (size_t)(w*32 + l31)*S_ + k0 + j*16 + h*8, (char*)Vl + (w*4+j)*1024);
    }
    __syncthreads();

    // S^T = K * Q^T : sf[mt][g], D[m=key][n=qrow]
    f32x16 sf[2][2];
    #pragma unroll
    for (int mt = 0; mt < 2; mt++)
      #pragma unroll
      for (int g = 0; g < 2; g++)
        #pragma unroll
        for (int r = 0; r < 16; r++) sf[mt][g][r] = 0.f;
    #pragma unroll
    for (int kk = 0; kk < 4; kk++) {
      bf16x8 ka0 = *(const bf16x8*)(Kl + (0*4+kk)*512 + l*8);
      bf16x8 ka1 = *(const bf16x8*)(Kl + (1*4+kk)*512 + l*8);
      sf[0][0] = MFMA32(ka0, qa[0][kk], sf[0][0]);
      sf[0][1] = MFMA32(ka0, qa[1][kk], sf[0][1]);
      sf[1][0] = MFMA32(ka1, qa[0][kk], sf[1][0]);
      sf[1][1] = MFMA32(ka1, qa[1][kk], sf[1][1]);
    }

    // online softmax; lane's q-row = g*32+l31 (dup across halves)
    float alpha[2];
    #pragma unroll
    for (int g = 0; g < 2; g++) {
      float tm = sf[0][g][0];
      #pragma unroll
      for (int r = 1; r < 16; r++) tm = fmaxf(tm, sf[0][g][r]);
      #pragma unroll
      for (int r = 0; r < 16; r++) tm = fmaxf(tm, sf[1][g][r]);
      tm = fmaxf(tm, __shfl_xor(tm, 32));
      float mn = fmaxf(m_[g], tm);
      alpha[g] = __builtin_amdgcn_exp2f(m_[g] - mn);
      m_[g] = mn;
      float s = 0.f;
      #pragma unroll
      for (int mt = 0; mt < 2; mt++)
        #pragma unroll
        for (int r = 0; r < 16; r++) {
          float p = __builtin_amdgcn_exp2f(sf[mt][g][r] - mn);
          sf[mt][g][r] = p;
          s += p;
        }
      s += __shfl_xor(s, 32);
      l_[g] = l_[g] * alpha[g] + s;
    }

    // rescale O by alpha (broadcast per-row via per-wave LDS)
    #pragma unroll
    for (int g = 0; g < 2; g++) redL[w][g*32 + l31] = alpha[g];
    #pragma unroll
    for (int g = 0; g < 2; g++)
      #pragma unroll
      for (int rb = 0; rb < 4; rb++) {
        f32x4 a4 = *(const f32x4*)&redL[w][g*32 + 8*rb + 4*h];
        #pragma unroll
        for (int c = 0; c < 4; c++) {
          int r = rb*4 + c;
          o[g][0][r] *= a4[c];
          o[g][1][r] *= a4[c];
        }
      }

    // pack P to bf16 pairs: pk[mt][g][e][f] = keys mt*32+4h+8e+2f+{0,1} at qrow g*32+l31
    unsigned int pk[2][2][4][2];
    #pragma unroll
    for (int mt = 0; mt < 2; mt++)
      #pragma unroll
      for (int g = 0; g < 2; g++)
        #pragma unroll
        for (int e = 0; e < 4; e++)
          #pragma unroll
          for (int f = 0; f < 2; f++)
            pk[mt][g][e][f] = packbf2(sf[mt][g][4*e + 2*f], sf[mt][g][4*e + 2*f + 1]);

    // O += P*V ; P A-frag assembled via half-wave exchange (no LDS round-trip)
    #pragma unroll
    for (int kk2 = 0; kk2 < 4; kk2++) {
      const int mt = kk2 >> 1, k1 = kk2 & 1;
      bf16x8 bv0 = *(const bf16x8*)(Vl + (0*4+kk2)*512 + l*8);
      bf16x8 bv1 = *(const bf16x8*)(Vl + (1*4+kk2)*512 + l*8);
      #pragma unroll
      for (int g = 0; g < 2; g++) {
        unsigned int s0_ = h ? pk[mt][g][2*k1][0] : pk[mt][g][2*k1+1][0];
        unsigned int s1_ = h ? pk[mt][g][2*k1][1] : pk[mt][g][2*k1+1][1];
        unsigned int r0 = (unsigned int)__shfl_xor((int)s0_, 32);
        unsigned int r1 = (unsigned int)__shfl_xor((int)s1_, 32);
        union { unsigned int u[4]; bf16x8 v; } pa;
        pa.u[0] = h ? r0 : pk[mt][g][2*k1][0];
        pa.u[1] = h ? r1 : pk[mt][g][2*k1][1];
        pa.u[2] = h ? pk[mt][g][2*k1+1][0] : r0;
        pa.u[3] = h ? pk[mt][g][2*k1+1][1] : r1;
        o[g][0] = MFMA32(pa.v, bv0, o[g][0]);
        o[g][1] = MFMA32(pa.v, bv1, o[g][1]);
      }
    }
  }

  // epilogue: normalize by 1/l (broadcast), write bf16 [token][h*64+hd]
  #pragma unroll
  for (int g = 0; g < 2; g++) redL[w][g*32 + l31] = 1.f / l_[g];
  #pragma unroll
  for (int g = 0; g < 2; g++)
    #pragma unroll
    for (int rb = 0; rb < 4; rb++) {
      f32x4 iv4 = *(const f32x4*)&redL[w][g*32 + 8*rb + 4*h];
      #pragma unroll
      for (int c = 0; c < 4; c++) {
        int r = rb*4 + c;
        int row = s0 + g*32 + c + 8*rb + 4*h;
        size_t off = ((size_t)(b*S_ + row)) * D_ + hh*64;
        ob[off + 0*32 + l31] = f2bf(o[g][0][r] * iv4[c]);
        ob[off + 1*32 + l31] = f2bf(o[g][1][r] * iv4[c]);
      }
    }
}

extern "C" void kernel_launch(void* const* d_in, const int* in_sizes, int n_in,
                              void* d_out, int out_size, void* d_ws, size_t ws_size,
                              hipStream_t stream) {
  const float* x      = (const float*)d_in[0];
  const float* w_qkv  = (const float*)d_in[1];
  const float* b_qkv  = (const float*)d_in[2];
  const float* w_proj = (const float*)d_in[3];
  const float* b_proj = (const float*)d_in[4];
  float* out = (float*)d_out;

  char* ws = (char*)d_ws;
  u16* xbf    = (u16*)ws; ws += (size_t)M_ * D_ * 2;
  u16* wqkvT  = (u16*)ws; ws += (size_t)3 * D_ * D_ * 2;
  u16* wprojT = (u16*)ws; ws += (size_t)D_ * D_ * 2;
  u16* qbuf   = (u16*)ws; ws += (size_t)M_ * D_ * 2;
  u16* kbuf   = (u16*)ws; ws += (size_t)M_ * D_ * 2;
  u16* vbuf   = (u16*)ws; ws += (size_t)M_ * D_ * 2;
  u16* vtbuf  = (u16*)ws; ws += (size_t)M_ * D_ * 2;
  u16* aobuf  = (u16*)ws; ws += (size_t)M_ * D_ * 2;

  cvt_f32_bf16<<<(M_ * D_ / 4 + 255) / 256, 256, 0, stream>>>(x, xbf, M_ * D_ / 4);
  transpose_w<<<dim3(3 * D_ / 32, D_ / 32), dim3(32, 8), 0, stream>>>(w_qkv, wqkvT, D_, 3 * D_);
  transpose_w<<<dim3(D_ / 32, D_ / 32), dim3(32, 8), 0, stream>>>(w_proj, wprojT, D_, D_);
  gemm_qkv<<<dim3(3 * D_ / 128, M_ / 128), 256, 0, stream>>>(xbf, wqkvT, b_qkv, qbuf, kbuf, vbuf);
  transpose_v<<<dim3(HD_ / 32, S_ / 32, B_ * H_), dim3(32, 8), 0, stream>>>(vbuf, vtbuf);
  attn<<<dim3(S_ / 128, B_ * H_), 128, 0, stream>>>(qbuf, kbuf, vtbuf, aobuf);
  gemm_proj<<<dim3(D_ / 128, M_ / 128), 256, 0, stream>>>(aobuf, wprojT, b_proj, out);
}